// Round 8
// baseline (192.610 us; speedup 1.0000x reference)
//
#include <hip/hip_runtime.h>
#include <hip/hip_bf16.h>
#include <math.h>

typedef __bf16 bf16_t;
typedef bf16_t bf16x4 __attribute__((ext_vector_type(4)));
typedef bf16_t bf16x8 __attribute__((ext_vector_type(8)));
typedef float f32x4 __attribute__((ext_vector_type(4)));

#define MFMA16(a, b, c) __builtin_amdgcn_mfma_f32_16x16x32_bf16(a, b, c, 0, 0, 0)
#define NEG_BIG (-1e30f)

// Async global->LDS, 16B per lane. LDS dest = wave-uniform base + lane*16.
#define GLL16(gp, lp)                                                          \
    __builtin_amdgcn_global_load_lds(                                          \
        (const __attribute__((address_space(1))) unsigned int*)(gp),           \
        (__attribute__((address_space(3))) unsigned int*)(lp), 16, 0, 0)

// XOR-swizzled LDS tiles: row stride 64 elems (128B), chunk c of row r at
// slot c^(r&7). Staging lane fetches global chunk (lane&7)^(lane>>3); reads
// use slot = chunk ^ (row&7) -> 2-way max bank aliasing (free, m136).

// ---------------------------------------------------------------------------
// Fused prep: z=4 -> cast x to bf16 (4 passes: 1024 blocks cover 4M elems);
// z=0..3 -> transpose+cast Wq/Wk/Wv/Wo. Grid (32,32,5), block (32,8).
// ---------------------------------------------------------------------------
__global__ __launch_bounds__(256) void prep(const float* __restrict__ x,
                                            const float* __restrict__ Wq,
                                            const float* __restrict__ Wk,
                                            const float* __restrict__ Wv,
                                            const float* __restrict__ Wo,
                                            bf16_t* __restrict__ Xb,
                                            bf16_t* __restrict__ WTqkv,
                                            bf16_t* __restrict__ WoT) {
    __shared__ float tile[32][33];
    const int z = blockIdx.z;
    const int tx = threadIdx.x, ty = threadIdx.y;
    if (z == 4) {
        // 1024 blocks x 256 threads x 4 elems x 4 passes = 4,194,304 = |x|
        int i0 = (((blockIdx.y * 32 + blockIdx.x) * 256) + ty * 32 + tx) * 4;
        for (int j = 0; j < 4; j++) {
            int i = i0 + j * 1048576;
            float4 v = *(const float4*)(x + i);
            Xb[i + 0] = (bf16_t)v.x;
            Xb[i + 1] = (bf16_t)v.y;
            Xb[i + 2] = (bf16_t)v.z;
            Xb[i + 3] = (bf16_t)v.w;
        }
    } else {
        const float* W = (z == 0) ? Wq : (z == 1) ? Wk : (z == 2) ? Wv : Wo;
        bf16_t* WT = (z < 3) ? (WTqkv + (size_t)z * 1048576) : WoT;
        int bx = blockIdx.x * 32, by = blockIdx.y * 32;
        for (int i = 0; i < 32; i += 8)
            tile[ty + i][tx] = W[(size_t)(by + ty + i) * 1024 + bx + tx];
        __syncthreads();
        for (int i = 0; i < 32; i += 8)
            WT[(size_t)(bx + ty + i) * 1024 + by + tx] = (bf16_t)tile[tx][ty + i];
    }
}

// ---------------------------------------------------------------------------
// QKV projection GEMM, m97-style global_load_lds staging.
// X:[4096][1024] bf16, WT:[3][1024][1024] bf16 (n-major)
// z=0 -> Q [32][2048][64], z=1 -> K [32][2048][64], z=2 -> V^T [32][64][2048]
// 128x128 tile, 4 waves 2x2, BK=64. z=2 swaps MFMA operands -> C^T epilogue
// writes V^T with s-contiguous (coalesced) segments.
// ---------------------------------------------------------------------------
__global__ __launch_bounds__(256) void gemm_qkv(const bf16_t* __restrict__ X,
                                                const bf16_t* __restrict__ WT,
                                                bf16_t* __restrict__ Qd,
                                                bf16_t* __restrict__ Kd,
                                                bf16_t* __restrict__ Vd) {
    __shared__ bf16_t AsmF[128 * 64];
    __shared__ bf16_t BsmF[128 * 64];
    const int which = blockIdx.z;
    const bf16_t* Wt = WT + (size_t)which * 1024 * 1024;
    const int bm = blockIdx.y * 128;
    const int bn = blockIdx.x * 128;
    const int tid = threadIdx.x;
    const int wave = tid >> 6, lane = tid & 63;
    const int wm = (wave >> 1) * 64, wn = (wave & 1) * 64;
    const int col = lane & 15, quad = lane >> 4;
    const int cswz = col & 7;
    const int lr8 = lane >> 3;
    const int jg = (lane & 7) ^ lr8;

    const int srow = wave * 32 + lr8;
    const bf16_t* gA = X  + (size_t)(bm + srow) * 1024 + jg * 8;
    const bf16_t* gB = Wt + (size_t)(bn + srow) * 1024 + jg * 8;
    bf16_t* lA = AsmF + wave * 2048;
    bf16_t* lB = BsmF + wave * 2048;

    f32x4 acc[4][4] = {};

    for (int k0 = 0; k0 < 1024; k0 += 64) {
        for (int j = 0; j < 4; j++) {
            GLL16(gA + (size_t)j * 8192 + k0, lA + j * 512);
            GLL16(gB + (size_t)j * 8192 + k0, lB + j * 512);
        }
        __syncthreads();
        for (int ks = 0; ks < 2; ks++) {
            bf16x8 af[4], bfr[4];
            for (int mi = 0; mi < 4; mi++)
                af[mi] = *(const bf16x8*)&AsmF[(wm + mi * 16 + col) * 64 +
                                               (((ks << 2) + quad) ^ cswz) * 8];
            for (int ni = 0; ni < 4; ni++)
                bfr[ni] = *(const bf16x8*)&BsmF[(wn + ni * 16 + col) * 64 +
                                                (((ks << 2) + quad) ^ cswz) * 8];
            if (which != 2) {
                for (int mi = 0; mi < 4; mi++)
                    for (int ni = 0; ni < 4; ni++)
                        acc[mi][ni] = MFMA16(af[mi], bfr[ni], acc[mi][ni]);
            } else {
                for (int mi = 0; mi < 4; mi++)
                    for (int ni = 0; ni < 4; ni++)
                        acc[mi][ni] = MFMA16(bfr[ni], af[mi], acc[mi][ni]);
            }
        }
        __syncthreads();
    }

    if (which != 2) {
        for (int mi = 0; mi < 4; mi++) {
            for (int ni = 0; ni < 4; ni++) {
                int mbase = bm + wm + mi * 16 + quad * 4;
                int n = bn + wn + ni * 16 + col;
                int h = n >> 6, dh = n & 63;
                for (int r = 0; r < 4; r++) {
                    int m = mbase + r;
                    int b = m >> 11, s = m & 2047;
                    size_t bh = (size_t)b * 16 + h;
                    bf16_t val = (bf16_t)acc[mi][ni][r];
                    if (which == 0) Qd[(bh * 2048 + s) * 64 + dh] = val;
                    else            Kd[(bh * 2048 + s) * 64 + dh] = val;
                }
            }
        }
    } else {
        for (int mi = 0; mi < 4; mi++) {
            for (int ni = 0; ni < 4; ni++) {
                int nbase = bn + wn + ni * 16 + quad * 4;
                int m = bm + wm + mi * 16 + col;
                int b = m >> 11, s = m & 2047;
                for (int r = 0; r < 4; r++) {
                    int n = nbase + r;
                    int h = n >> 6, dh = n & 63;
                    size_t bh = (size_t)b * 16 + h;
                    Vd[(bh * 64 + dh) * 2048 + s] = (bf16_t)acc[mi][ni][r];
                }
            }
        }
    }
}

// ---------------------------------------------------------------------------
// Flash attention (causal): pairing + slim softmax + TRUE prefetch pipeline
// + XCD-local bh mapping. 1-D grid of 512: bh = b&31 (so block%8 = bh%8 ->
// all 16 pair-blocks of a bh share one XCD's L2), pr = b>>5.
// Flat 33-iteration loop over both phases; stage(g+1) issued right after the
// barrier that (a) makes buf[g] ready and (b) retires readers of buf[g+1].
// ---------------------------------------------------------------------------
#define PSD 72
__global__ __launch_bounds__(256) void attn(const bf16_t* __restrict__ Q,
                                            const bf16_t* __restrict__ K,
                                            const bf16_t* __restrict__ VT,
                                            bf16_t* __restrict__ CTX) {
    __shared__ bf16_t KsF[2 * 64 * 64];
    __shared__ bf16_t VsF[2 * 64 * 64];
    __shared__ bf16_t Ps[4][16][PSD];

    const int bidx = blockIdx.x;
    const int bh = bidx & 31;        // XCD-local: bidx%8 == bh%8
    const int pr = bidx >> 5;        // 0..15
    const int qt0 = pr, qt1 = 31 - pr;
    const int tid = threadIdx.x;
    const int wave = tid >> 6, lane = tid & 63;
    const int col = lane & 15, quad = lane >> 4;
    const int cswz = col & 7;
    const int lr8 = lane >> 3;
    const int jg = (lane & 7) ^ lr8;

    const bf16_t* Qb = Q + (size_t)bh * 2048 * 64;
    const bf16_t* Kb = K + (size_t)bh * 2048 * 64;
    const bf16_t* Vb = VT + (size_t)bh * 64 * 2048;

    const int strow = wave * 16 + lr8;
    const bf16_t* gK = Kb + (size_t)strow * 64 + jg * 8;
    const bf16_t* gV = Vb + (size_t)strow * 2048 + jg * 8;

    const int b_ = bh >> 4, h_ = bh & 15;

    auto stage = [&](int k0, int bsel) {
        bf16_t* lK = KsF + bsel * 4096 + wave * 1024;
        bf16_t* lV = VsF + bsel * 4096 + wave * 1024;
        for (int j = 0; j < 2; j++) {
            GLL16(gK + (size_t)(k0 + j * 8) * 64, lK + j * 512);
            GLL16(gV + (size_t)(k0 + j * 8 * 2048), lV + j * 512);
        }
    };

    stage(0, 0);  // prologue

    int q0 = qt0 * 64;
    int qrow = q0 + wave * 16 + col;
    bf16x8 qf0 = *(const bf16x8*)&Qb[(size_t)qrow * 64 + quad * 8];
    bf16x8 qf1 = *(const bf16x8*)&Qb[(size_t)qrow * 64 + 32 + quad * 8];

    f32x4 o[4] = {};
    float lsum = 0.f;

    for (int g = 0; g < 33; g++) {
        __syncthreads();   // buf[g&1] ready; compute(g-1) done -> buf[(g+1)&1] free
        if (g < 32) {
            int gn = g + 1;
            int k0n = (gn <= qt0 ? gn : gn - qt0 - 1) * 64;
            stage(k0n, gn & 1);
        }

        const int bsel = g & 1;
        const bf16_t* Kbuf = KsF + bsel * 4096;
        const bf16_t* Vbuf = VsF + bsel * 4096;
        const bool diag = (g == qt0) || (g == 32);

        for (int ksub = 0; ksub < 4; ksub++) {
            bf16x8 a0 = *(const bf16x8*)&Kbuf[(ksub * 16 + col) * 64 +
                                              (quad ^ cswz) * 8];
            bf16x8 a1 = *(const bf16x8*)&Kbuf[(ksub * 16 + col) * 64 +
                                              ((4 + quad) ^ cswz) * 8];
            f32x4 z = {};
            z = MFMA16(a0, qf0, z);   // S^T: rows=key, cols=q
            z = MFMA16(a1, qf1, z);
            if (diag) {
                for (int r = 0; r < 4; r++) {
                    int lk = ksub * 16 + quad * 4 + r;
                    if (lk > wave * 16 + col) z[r] = NEG_BIG;
                }
            }
            bf16x4 pw;
            for (int r = 0; r < 4; r++) {
                float p = exp2f(z[r] * 0.18033688f);  // exp(z*0.125)
                lsum += p;
                pw[r] = (bf16_t)p;
            }
            *(bf16x4*)&Ps[wave][col][ksub * 16 + quad * 4] = pw;
        }

        for (int ck = 0; ck < 2; ck++) {
            bf16x8 pf = *(const bf16x8*)&Ps[wave][col][ck * 32 + quad * 8];
            for (int d = 0; d < 4; d++) {
                bf16x8 vf = *(const bf16x8*)&Vbuf[(d * 16 + col) * 64 +
                                                  (((ck << 2) + quad) ^ cswz) * 8];
                o[d] = MFMA16(pf, vf, o[d]);
            }
        }

        if (g == qt0) {
            // phase-0 epilogue + switch to phase 1
            float lt = lsum + __shfl_xor(lsum, 16, 64);
            lt += __shfl_xor(lt, 32, 64);
            for (int d = 0; d < 4; d++) {
                for (int r = 0; r < 4; r++) {
                    float lq = __shfl(lt, quad * 4 + r, 64);
                    int s = q0 + wave * 16 + quad * 4 + r;
                    CTX[((size_t)(b_ * 2048 + s)) * 1024 + h_ * 64 + d * 16 + col] =
                        (bf16_t)(o[d][r] / fmaxf(lq, 1e-20f));
                }
                o[d] = f32x4{};
            }
            lsum = 0.f;
            q0 = qt1 * 64;
            qrow = q0 + wave * 16 + col;
            qf0 = *(const bf16x8*)&Qb[(size_t)qrow * 64 + quad * 8];
            qf1 = *(const bf16x8*)&Qb[(size_t)qrow * 64 + 32 + quad * 8];
        }
    }

    // phase-1 epilogue
    float lt = lsum + __shfl_xor(lsum, 16, 64);
    lt += __shfl_xor(lt, 32, 64);
    for (int d = 0; d < 4; d++) {
        for (int r = 0; r < 4; r++) {
            float lq = __shfl(lt, quad * 4 + r, 64);
            int s = q0 + wave * 16 + quad * 4 + r;
            CTX[((size_t)(b_ * 2048 + s)) * 1024 + h_ * 64 + d * 16 + col] =
                (bf16_t)(o[d][r] / fmaxf(lq, 1e-20f));
        }
    }
}

// ---------------------------------------------------------------------------
// Output GEMM: OUT = CTX @ Wo + bo. 64x128 tile (512 blocks), BK=64,
// global_load_lds staging. Waves 2x2 of 32x64.
// ---------------------------------------------------------------------------
__global__ __launch_bounds__(256) void gemm_out(const bf16_t* __restrict__ X,
                                                const bf16_t* __restrict__ WT,
                                                const float* __restrict__ BO,
                                                float* __restrict__ OUT) {
    __shared__ bf16_t AsmF[64 * 64];
    __shared__ bf16_t BsmF[128 * 64];
    const int bm = blockIdx.y * 64;
    const int bn = blockIdx.x * 128;
    const int tid = threadIdx.x;
    const int wave = tid >> 6, lane = tid & 63;
    const int wm = (wave >> 1) * 32, wn = (wave & 1) * 64;
    const int col = lane & 15, quad = lane >> 4;
    const int cswz = col & 7;
    const int lr8 = lane >> 3;
    const int jg = (lane & 7) ^ lr8;

    const int arow = wave * 16 + lr8;
    const int brow = wave * 32 + lr8;
    const bf16_t* gA = X  + (size_t)(bm + arow) * 1024 + jg * 8;
    const bf16_t* gB = WT + (size_t)(bn + brow) * 1024 + jg * 8;
    bf16_t* lA = AsmF + wave * 1024;
    bf16_t* lB = BsmF + wave * 2048;

    f32x4 acc[2][4] = {};

    for (int k0 = 0; k0 < 1024; k0 += 64) {
        for (int j = 0; j < 2; j++)
            GLL16(gA + (size_t)j * 8192 + k0, lA + j * 512);
        for (int j = 0; j < 4; j++)
            GLL16(gB + (size_t)j * 8192 + k0, lB + j * 512);
        __syncthreads();
        for (int ks = 0; ks < 2; ks++) {
            bf16x8 af[2], bfr[4];
            for (int mi = 0; mi < 2; mi++)
                af[mi] = *(const bf16x8*)&AsmF[(wm + mi * 16 + col) * 64 +
                                               (((ks << 2) + quad) ^ cswz) * 8];
            for (int ni = 0; ni < 4; ni++)
                bfr[ni] = *(const bf16x8*)&BsmF[(wn + ni * 16 + col) * 64 +
                                                (((ks << 2) + quad) ^ cswz) * 8];
            for (int mi = 0; mi < 2; mi++)
                for (int ni = 0; ni < 4; ni++)
                    acc[mi][ni] = MFMA16(af[mi], bfr[ni], acc[mi][ni]);
        }
        __syncthreads();
    }

    for (int mi = 0; mi < 2; mi++) {
        for (int ni = 0; ni < 4; ni++) {
            int mbase = bm + wm + mi * 16 + quad * 4;
            int n = bn + wn + ni * 16 + col;
            float bov = BO[n];
            for (int r = 0; r < 4; r++) {
                int m = mbase + r;
                OUT[(size_t)m * 1024 + n] = acc[mi][ni][r] + bov;
            }
        }
    }
}

// ---------------------------------------------------------------------------
extern "C" void kernel_launch(void* const* d_in, const int* in_sizes, int n_in,
                              void* d_out, int out_size, void* d_ws, size_t ws_size,
                              hipStream_t stream) {
    const float* x  = (const float*)d_in[0];
    const float* Wq = (const float*)d_in[1];
    const float* Wk = (const float*)d_in[2];
    const float* Wv = (const float*)d_in[3];
    const float* Wo = (const float*)d_in[4];
    const float* bo = (const float*)d_in[5];
    float* out = (float*)d_out;

    const size_t MEG = 1048576;
    bf16_t* base  = (bf16_t*)d_ws;
    bf16_t* Xb    = base;                 // 4M elems  [4096][1024]
    bf16_t* WTqkv = base + 4 * MEG;       // 3M (WqT, WkT, WvT)
    bf16_t* WoT   = base + 7 * MEG;       // 1M
    bf16_t* Qb    = base + 8 * MEG;       // 4M  [32][2048][64]
    bf16_t* Kb    = base + 12 * MEG;      // 4M
    bf16_t* Vb    = base + 16 * MEG;      // 4M  [32][64][2048]
    bf16_t* Cb    = base + 20 * MEG;      // 4M  [4096][1024]

    prep<<<dim3(32, 32, 5), dim3(32, 8), 0, stream>>>(x, Wq, Wk, Wv, Wo,
                                                      Xb, WTqkv, WoT);
    gemm_qkv<<<dim3(8, 32, 3), 256, 0, stream>>>(Xb, WTqkv, Qb, Kb, Vb);
    attn<<<512, 256, 0, stream>>>(Qb, Kb, Vb, Cb);
    gemm_out<<<dim3(8, 64), 256, 0, stream>>>(Cb, WoT, bo, out);
}

// Round 9
// 189.796 us; speedup vs baseline: 1.0148x; 1.0148x over previous
//
#include <hip/hip_runtime.h>
#include <hip/hip_bf16.h>
#include <math.h>

typedef __bf16 bf16_t;
typedef bf16_t bf16x4 __attribute__((ext_vector_type(4)));
typedef bf16_t bf16x8 __attribute__((ext_vector_type(8)));
typedef float f32x4 __attribute__((ext_vector_type(4)));

#define MFMA16(a, b, c) __builtin_amdgcn_mfma_f32_16x16x32_bf16(a, b, c, 0, 0, 0)
#define NEG_BIG (-1e30f)
#define QSCALE 0.18033688f   // log2(e) / sqrt(64): folded into Q at projection

// Async global->LDS, 16B per lane. LDS dest = wave-uniform base + lane*16.
#define GLL16(gp, lp)                                                          \
    __builtin_amdgcn_global_load_lds(                                          \
        (const __attribute__((address_space(1))) unsigned int*)(gp),           \
        (__attribute__((address_space(3))) unsigned int*)(lp), 16, 0, 0)

// XOR-swizzled LDS tiles: row stride 64 elems (128B), chunk c of row r at
// slot c^(r&7). Staging lane fetches global chunk (lane&7)^(lane>>3); reads
// use slot = chunk ^ (row&7) -> 2-way max bank aliasing (free, m136).

// ---------------------------------------------------------------------------
// Fused prep: z=4 -> cast x to bf16 (4 passes: 1024 blocks cover 4M elems);
// z=0..3 -> transpose+cast Wq/Wk/Wv/Wo. Grid (32,32,5), block (32,8).
// ---------------------------------------------------------------------------
__global__ __launch_bounds__(256) void prep(const float* __restrict__ x,
                                            const float* __restrict__ Wq,
                                            const float* __restrict__ Wk,
                                            const float* __restrict__ Wv,
                                            const float* __restrict__ Wo,
                                            bf16_t* __restrict__ Xb,
                                            bf16_t* __restrict__ WTqkv,
                                            bf16_t* __restrict__ WoT) {
    __shared__ float tile[32][33];
    const int z = blockIdx.z;
    const int tx = threadIdx.x, ty = threadIdx.y;
    if (z == 4) {
        int i0 = (((blockIdx.y * 32 + blockIdx.x) * 256) + ty * 32 + tx) * 4;
        for (int j = 0; j < 4; j++) {
            int i = i0 + j * 1048576;
            float4 v = *(const float4*)(x + i);
            Xb[i + 0] = (bf16_t)v.x;
            Xb[i + 1] = (bf16_t)v.y;
            Xb[i + 2] = (bf16_t)v.z;
            Xb[i + 3] = (bf16_t)v.w;
        }
    } else {
        const float* W = (z == 0) ? Wq : (z == 1) ? Wk : (z == 2) ? Wv : Wo;
        bf16_t* WT = (z < 3) ? (WTqkv + (size_t)z * 1048576) : WoT;
        int bx = blockIdx.x * 32, by = blockIdx.y * 32;
        for (int i = 0; i < 32; i += 8)
            tile[ty + i][tx] = W[(size_t)(by + ty + i) * 1024 + bx + tx];
        __syncthreads();
        for (int i = 0; i < 32; i += 8)
            WT[(size_t)(bx + ty + i) * 1024 + by + tx] = (bf16_t)tile[tx][ty + i];
    }
}

// ---------------------------------------------------------------------------
// QKV projection GEMM, m97-style global_load_lds staging.
// X:[4096][1024] bf16, WT:[3][1024][1024] bf16 (n-major)
// z=0 -> Q*QSCALE [32][2048][64], z=1 -> K, z=2 -> V^T [32][64][2048]
// 128x128 tile, 4 waves 2x2, BK=64. z=2 swaps MFMA operands -> C^T epilogue
// writes V^T with s-contiguous (coalesced) segments.
// ---------------------------------------------------------------------------
__global__ __launch_bounds__(256) void gemm_qkv(const bf16_t* __restrict__ X,
                                                const bf16_t* __restrict__ WT,
                                                bf16_t* __restrict__ Qd,
                                                bf16_t* __restrict__ Kd,
                                                bf16_t* __restrict__ Vd) {
    __shared__ bf16_t AsmF[128 * 64];
    __shared__ bf16_t BsmF[128 * 64];
    const int which = blockIdx.z;
    const bf16_t* Wt = WT + (size_t)which * 1024 * 1024;
    const int bm = blockIdx.y * 128;
    const int bn = blockIdx.x * 128;
    const int tid = threadIdx.x;
    const int wave = tid >> 6, lane = tid & 63;
    const int wm = (wave >> 1) * 64, wn = (wave & 1) * 64;
    const int col = lane & 15, quad = lane >> 4;
    const int cswz = col & 7;
    const int lr8 = lane >> 3;
    const int jg = (lane & 7) ^ lr8;

    const int srow = wave * 32 + lr8;
    const bf16_t* gA = X  + (size_t)(bm + srow) * 1024 + jg * 8;
    const bf16_t* gB = Wt + (size_t)(bn + srow) * 1024 + jg * 8;
    bf16_t* lA = AsmF + wave * 2048;
    bf16_t* lB = BsmF + wave * 2048;

    f32x4 acc[4][4] = {};

    for (int k0 = 0; k0 < 1024; k0 += 64) {
        for (int j = 0; j < 4; j++) {
            GLL16(gA + (size_t)j * 8192 + k0, lA + j * 512);
            GLL16(gB + (size_t)j * 8192 + k0, lB + j * 512);
        }
        __syncthreads();
        for (int ks = 0; ks < 2; ks++) {
            bf16x8 af[4], bfr[4];
            for (int mi = 0; mi < 4; mi++)
                af[mi] = *(const bf16x8*)&AsmF[(wm + mi * 16 + col) * 64 +
                                               (((ks << 2) + quad) ^ cswz) * 8];
            for (int ni = 0; ni < 4; ni++)
                bfr[ni] = *(const bf16x8*)&BsmF[(wn + ni * 16 + col) * 64 +
                                                (((ks << 2) + quad) ^ cswz) * 8];
            if (which != 2) {
                for (int mi = 0; mi < 4; mi++)
                    for (int ni = 0; ni < 4; ni++)
                        acc[mi][ni] = MFMA16(af[mi], bfr[ni], acc[mi][ni]);
            } else {
                for (int mi = 0; mi < 4; mi++)
                    for (int ni = 0; ni < 4; ni++)
                        acc[mi][ni] = MFMA16(bfr[ni], af[mi], acc[mi][ni]);
            }
        }
        __syncthreads();
    }

    if (which != 2) {
        const float sc = (which == 0) ? QSCALE : 1.0f;
        for (int mi = 0; mi < 4; mi++) {
            for (int ni = 0; ni < 4; ni++) {
                int mbase = bm + wm + mi * 16 + quad * 4;
                int n = bn + wn + ni * 16 + col;
                int h = n >> 6, dh = n & 63;
                for (int r = 0; r < 4; r++) {
                    int m = mbase + r;
                    int b = m >> 11, s = m & 2047;
                    size_t bh = (size_t)b * 16 + h;
                    bf16_t val = (bf16_t)(acc[mi][ni][r] * sc);
                    if (which == 0) Qd[(bh * 2048 + s) * 64 + dh] = val;
                    else            Kd[(bh * 2048 + s) * 64 + dh] = val;
                }
            }
        }
    } else {
        for (int mi = 0; mi < 4; mi++) {
            for (int ni = 0; ni < 4; ni++) {
                int nbase = bn + wn + ni * 16 + quad * 4;
                int m = bm + wm + mi * 16 + col;
                int b = m >> 11, s = m & 2047;
                for (int r = 0; r < 4; r++) {
                    int n = nbase + r;
                    int h = n >> 6, dh = n & 63;
                    size_t bh = (size_t)b * 16 + h;
                    Vd[(bh * 64 + dh) * 2048 + s] = (bf16_t)acc[mi][ni][r];
                }
            }
        }
    }
}

// ---------------------------------------------------------------------------
// Flash attention (causal): pairing + prefetch pipeline + XCD-local bh map.
// Slim softmax v2: Q pre-scaled (exp2f direct), l computed by ones-MFMA
// (accl C-layout reg r == row q = quad*4+r, matching o's rows exactly).
// ---------------------------------------------------------------------------
#define PSD 72
__global__ __launch_bounds__(256) void attn(const bf16_t* __restrict__ Q,
                                            const bf16_t* __restrict__ K,
                                            const bf16_t* __restrict__ VT,
                                            bf16_t* __restrict__ CTX) {
    __shared__ bf16_t KsF[2 * 64 * 64];
    __shared__ bf16_t VsF[2 * 64 * 64];
    __shared__ bf16_t Ps[4][16][PSD];

    const int bidx = blockIdx.x;
    const int bh = bidx & 31;        // XCD-local: bidx%8 == bh%8
    const int pr = bidx >> 5;        // 0..15
    const int qt0 = pr, qt1 = 31 - pr;
    const int tid = threadIdx.x;
    const int wave = tid >> 6, lane = tid & 63;
    const int col = lane & 15, quad = lane >> 4;
    const int cswz = col & 7;
    const int lr8 = lane >> 3;
    const int jg = (lane & 7) ^ lr8;

    const bf16_t* Qb = Q + (size_t)bh * 2048 * 64;
    const bf16_t* Kb = K + (size_t)bh * 2048 * 64;
    const bf16_t* Vb = VT + (size_t)bh * 64 * 2048;

    const int strow = wave * 16 + lr8;
    const bf16_t* gK = Kb + (size_t)strow * 64 + jg * 8;
    const bf16_t* gV = Vb + (size_t)strow * 2048 + jg * 8;

    const int b_ = bh >> 4, h_ = bh & 15;

    bf16x8 ones;
    for (int i = 0; i < 8; i++) ones[i] = (bf16_t)1.0f;

    auto stage = [&](int k0, int bsel) {
        bf16_t* lK = KsF + bsel * 4096 + wave * 1024;
        bf16_t* lV = VsF + bsel * 4096 + wave * 1024;
        for (int j = 0; j < 2; j++) {
            GLL16(gK + (size_t)(k0 + j * 8) * 64, lK + j * 512);
            GLL16(gV + (size_t)(k0 + j * 8 * 2048), lV + j * 512);
        }
    };

    stage(0, 0);  // prologue

    int q0 = qt0 * 64;
    int qrow = q0 + wave * 16 + col;
    bf16x8 qf0 = *(const bf16x8*)&Qb[(size_t)qrow * 64 + quad * 8];
    bf16x8 qf1 = *(const bf16x8*)&Qb[(size_t)qrow * 64 + 32 + quad * 8];

    f32x4 o[4] = {};
    f32x4 accl = {};   // l[q]: reg r holds l[quad*4+r], replicated over cols

    for (int g = 0; g < 33; g++) {
        __syncthreads();   // buf[g&1] ready; compute(g-1) done -> buf[(g+1)&1] free
        if (g < 32) {
            int gn = g + 1;
            int k0n = (gn <= qt0 ? gn : gn - qt0 - 1) * 64;
            stage(k0n, gn & 1);
        }

        const int bsel = g & 1;
        const bf16_t* Kbuf = KsF + bsel * 4096;
        const bf16_t* Vbuf = VsF + bsel * 4096;
        const bool diag = (g == qt0) || (g == 32);

        for (int ksub = 0; ksub < 4; ksub++) {
            bf16x8 a0 = *(const bf16x8*)&Kbuf[(ksub * 16 + col) * 64 +
                                              (quad ^ cswz) * 8];
            bf16x8 a1 = *(const bf16x8*)&Kbuf[(ksub * 16 + col) * 64 +
                                              ((4 + quad) ^ cswz) * 8];
            f32x4 z = {};
            z = MFMA16(a0, qf0, z);   // S^T: rows=key, cols=q (Q pre-scaled)
            z = MFMA16(a1, qf1, z);
            if (diag) {
                for (int r = 0; r < 4; r++) {
                    int lk = ksub * 16 + quad * 4 + r;
                    if (lk > wave * 16 + col) z[r] = NEG_BIG;
                }
            }
            bf16x4 pw;
            for (int r = 0; r < 4; r++)
                pw[r] = (bf16_t)exp2f(z[r]);   // p = e^{qk/8}; masked -> 0
            *(bf16x4*)&Ps[wave][col][ksub * 16 + quad * 4] = pw;
        }

        for (int ck = 0; ck < 2; ck++) {
            bf16x8 pf = *(const bf16x8*)&Ps[wave][col][ck * 32 + quad * 8];
            accl = MFMA16(pf, ones, accl);     // l[q] += sum_k P[q][k]
            for (int d = 0; d < 4; d++) {
                bf16x8 vf = *(const bf16x8*)&Vbuf[(d * 16 + col) * 64 +
                                                  (((ck << 2) + quad) ^ cswz) * 8];
                o[d] = MFMA16(pf, vf, o[d]);
            }
        }

        if (g == qt0) {
            // phase-0 epilogue + switch to phase 1
            for (int d = 0; d < 4; d++) {
                for (int r = 0; r < 4; r++) {
                    int s = q0 + wave * 16 + quad * 4 + r;
                    CTX[((size_t)(b_ * 2048 + s)) * 1024 + h_ * 64 + d * 16 + col] =
                        (bf16_t)(o[d][r] / fmaxf(accl[r], 1e-20f));
                }
                o[d] = f32x4{};
            }
            accl = f32x4{};
            q0 = qt1 * 64;
            qrow = q0 + wave * 16 + col;
            qf0 = *(const bf16x8*)&Qb[(size_t)qrow * 64 + quad * 8];
            qf1 = *(const bf16x8*)&Qb[(size_t)qrow * 64 + 32 + quad * 8];
        }
    }

    // phase-1 epilogue
    for (int d = 0; d < 4; d++) {
        for (int r = 0; r < 4; r++) {
            int s = q0 + wave * 16 + quad * 4 + r;
            CTX[((size_t)(b_ * 2048 + s)) * 1024 + h_ * 64 + d * 16 + col] =
                (bf16_t)(o[d][r] / fmaxf(accl[r], 1e-20f));
        }
    }
}

// ---------------------------------------------------------------------------
// Output GEMM: OUT = CTX @ Wo + bo. 64x128 tile (512 blocks), BK=64,
// global_load_lds staging. Waves 2x2 of 32x64.
// ---------------------------------------------------------------------------
__global__ __launch_bounds__(256) void gemm_out(const bf16_t* __restrict__ X,
                                                const bf16_t* __restrict__ WT,
                                                const float* __restrict__ BO,
                                                float* __restrict__ OUT) {
    __shared__ bf16_t AsmF[64 * 64];
    __shared__ bf16_t BsmF[128 * 64];
    const int bm = blockIdx.y * 64;
    const int bn = blockIdx.x * 128;
    const int tid = threadIdx.x;
    const int wave = tid >> 6, lane = tid & 63;
    const int wm = (wave >> 1) * 32, wn = (wave & 1) * 64;
    const int col = lane & 15, quad = lane >> 4;
    const int cswz = col & 7;
    const int lr8 = lane >> 3;
    const int jg = (lane & 7) ^ lr8;

    const int arow = wave * 16 + lr8;
    const int brow = wave * 32 + lr8;
    const bf16_t* gA = X  + (size_t)(bm + arow) * 1024 + jg * 8;
    const bf16_t* gB = WT + (size_t)(bn + brow) * 1024 + jg * 8;
    bf16_t* lA = AsmF + wave * 1024;
    bf16_t* lB = BsmF + wave * 2048;

    f32x4 acc[2][4] = {};

    for (int k0 = 0; k0 < 1024; k0 += 64) {
        for (int j = 0; j < 2; j++)
            GLL16(gA + (size_t)j * 8192 + k0, lA + j * 512);
        for (int j = 0; j < 4; j++)
            GLL16(gB + (size_t)j * 8192 + k0, lB + j * 512);
        __syncthreads();
        for (int ks = 0; ks < 2; ks++) {
            bf16x8 af[2], bfr[4];
            for (int mi = 0; mi < 2; mi++)
                af[mi] = *(const bf16x8*)&AsmF[(wm + mi * 16 + col) * 64 +
                                               (((ks << 2) + quad) ^ cswz) * 8];
            for (int ni = 0; ni < 4; ni++)
                bfr[ni] = *(const bf16x8*)&BsmF[(wn + ni * 16 + col) * 64 +
                                                (((ks << 2) + quad) ^ cswz) * 8];
            for (int mi = 0; mi < 2; mi++)
                for (int ni = 0; ni < 4; ni++)
                    acc[mi][ni] = MFMA16(af[mi], bfr[ni], acc[mi][ni]);
        }
        __syncthreads();
    }

    for (int mi = 0; mi < 2; mi++) {
        for (int ni = 0; ni < 4; ni++) {
            int mbase = bm + wm + mi * 16 + quad * 4;
            int n = bn + wn + ni * 16 + col;
            float bov = BO[n];
            for (int r = 0; r < 4; r++) {
                int m = mbase + r;
                OUT[(size_t)m * 1024 + n] = acc[mi][ni][r] + bov;
            }
        }
    }
}

// ---------------------------------------------------------------------------
extern "C" void kernel_launch(void* const* d_in, const int* in_sizes, int n_in,
                              void* d_out, int out_size, void* d_ws, size_t ws_size,
                              hipStream_t stream) {
    const float* x  = (const float*)d_in[0];
    const float* Wq = (const float*)d_in[1];
    const float* Wk = (const float*)d_in[2];
    const float* Wv = (const float*)d_in[3];
    const float* Wo = (const float*)d_in[4];
    const float* bo = (const float*)d_in[5];
    float* out = (float*)d_out;

    const size_t MEG = 1048576;
    bf16_t* base  = (bf16_t*)d_ws;
    bf16_t* Xb    = base;                 // 4M elems  [4096][1024]
    bf16_t* WTqkv = base + 4 * MEG;       // 3M (WqT, WkT, WvT)
    bf16_t* WoT   = base + 7 * MEG;       // 1M
    bf16_t* Qb    = base + 8 * MEG;       // 4M  [32][2048][64]
    bf16_t* Kb    = base + 12 * MEG;      // 4M
    bf16_t* Vb    = base + 16 * MEG;      // 4M  [32][64][2048]
    bf16_t* Cb    = base + 20 * MEG;      // 4M  [4096][1024]

    prep<<<dim3(32, 32, 5), dim3(32, 8), 0, stream>>>(x, Wq, Wk, Wv, Wo,
                                                      Xb, WTqkv, WoT);
    gemm_qkv<<<dim3(8, 32, 3), 256, 0, stream>>>(Xb, WTqkv, Qb, Kb, Vb);
    attn<<<512, 256, 0, stream>>>(Qb, Kb, Vb, Cb);
    gemm_out<<<dim3(8, 64), 256, 0, stream>>>(Cb, WoT, bo, out);
}

// Round 10
// 180.084 us; speedup vs baseline: 1.0696x; 1.0539x over previous
//
#include <hip/hip_runtime.h>
#include <hip/hip_bf16.h>
#include <math.h>

typedef __bf16 bf16_t;
typedef bf16_t bf16x4 __attribute__((ext_vector_type(4)));
typedef bf16_t bf16x8 __attribute__((ext_vector_type(8)));
typedef float f32x4 __attribute__((ext_vector_type(4)));

#define MFMA16(a, b, c) __builtin_amdgcn_mfma_f32_16x16x32_bf16(a, b, c, 0, 0, 0)
#define NEG_BIG (-1e30f)
#define QSCALE 0.18033688f   // log2(e) / sqrt(64): folded into Q at projection

// Async global->LDS, 16B per lane. LDS dest = wave-uniform base + lane*16.
#define GLL16(gp, lp)                                                          \
    __builtin_amdgcn_global_load_lds(                                          \
        (const __attribute__((address_space(1))) unsigned int*)(gp),           \
        (__attribute__((address_space(3))) unsigned int*)(lp), 16, 0, 0)

// XOR-swizzled LDS tiles: row stride 64 elems (128B), chunk c of row r at
// slot c^(r&7). Staging lane fetches global chunk (lane&7)^(lane>>3); reads
// use slot = chunk ^ (row&7) -> 2-way max bank aliasing (free, m136).

// ---------------------------------------------------------------------------
// Fused prep: z=4 -> cast x to bf16 (4 passes: 1024 blocks cover 4M elems);
// z=0..3 -> transpose+cast Wq/Wk/Wv/Wo. Grid (32,32,5), block (32,8).
// ---------------------------------------------------------------------------
__global__ __launch_bounds__(256) void prep(const float* __restrict__ x,
                                            const float* __restrict__ Wq,
                                            const float* __restrict__ Wk,
                                            const float* __restrict__ Wv,
                                            const float* __restrict__ Wo,
                                            bf16_t* __restrict__ Xb,
                                            bf16_t* __restrict__ WTqkv,
                                            bf16_t* __restrict__ WoT) {
    __shared__ float tile[32][33];
    const int z = blockIdx.z;
    const int tx = threadIdx.x, ty = threadIdx.y;
    if (z == 4) {
        int i0 = (((blockIdx.y * 32 + blockIdx.x) * 256) + ty * 32 + tx) * 4;
        for (int j = 0; j < 4; j++) {
            int i = i0 + j * 1048576;
            float4 v = *(const float4*)(x + i);
            Xb[i + 0] = (bf16_t)v.x;
            Xb[i + 1] = (bf16_t)v.y;
            Xb[i + 2] = (bf16_t)v.z;
            Xb[i + 3] = (bf16_t)v.w;
        }
    } else {
        const float* W = (z == 0) ? Wq : (z == 1) ? Wk : (z == 2) ? Wv : Wo;
        bf16_t* WT = (z < 3) ? (WTqkv + (size_t)z * 1048576) : WoT;
        int bx = blockIdx.x * 32, by = blockIdx.y * 32;
        for (int i = 0; i < 32; i += 8)
            tile[ty + i][tx] = W[(size_t)(by + ty + i) * 1024 + bx + tx];
        __syncthreads();
        for (int i = 0; i < 32; i += 8)
            WT[(size_t)(bx + ty + i) * 1024 + by + tx] = (bf16_t)tile[tx][ty + i];
    }
}

// ---------------------------------------------------------------------------
// QKV projection GEMM, m97-style global_load_lds staging.
// X:[4096][1024] bf16, WT:[3][1024][1024] bf16 (n-major)
// z=0 -> Q*QSCALE [32][2048][64], z=1 -> K, z=2 -> V^T [32][64][2048]
// 128x128 tile, 4 waves 2x2, BK=64. z=2 swaps MFMA operands -> C^T epilogue
// writes V^T with s-contiguous (coalesced) segments.
// ---------------------------------------------------------------------------
__global__ __launch_bounds__(256) void gemm_qkv(const bf16_t* __restrict__ X,
                                                const bf16_t* __restrict__ WT,
                                                bf16_t* __restrict__ Qd,
                                                bf16_t* __restrict__ Kd,
                                                bf16_t* __restrict__ Vd) {
    __shared__ bf16_t AsmF[128 * 64];
    __shared__ bf16_t BsmF[128 * 64];
    const int which = blockIdx.z;
    const bf16_t* Wt = WT + (size_t)which * 1024 * 1024;
    const int bm = blockIdx.y * 128;
    const int bn = blockIdx.x * 128;
    const int tid = threadIdx.x;
    const int wave = tid >> 6, lane = tid & 63;
    const int wm = (wave >> 1) * 64, wn = (wave & 1) * 64;
    const int col = lane & 15, quad = lane >> 4;
    const int cswz = col & 7;
    const int lr8 = lane >> 3;
    const int jg = (lane & 7) ^ lr8;

    const int srow = wave * 32 + lr8;
    const bf16_t* gA = X  + (size_t)(bm + srow) * 1024 + jg * 8;
    const bf16_t* gB = Wt + (size_t)(bn + srow) * 1024 + jg * 8;
    bf16_t* lA = AsmF + wave * 2048;
    bf16_t* lB = BsmF + wave * 2048;

    f32x4 acc[4][4] = {};

    for (int k0 = 0; k0 < 1024; k0 += 64) {
        for (int j = 0; j < 4; j++) {
            GLL16(gA + (size_t)j * 8192 + k0, lA + j * 512);
            GLL16(gB + (size_t)j * 8192 + k0, lB + j * 512);
        }
        __syncthreads();
        for (int ks = 0; ks < 2; ks++) {
            bf16x8 af[4], bfr[4];
            for (int mi = 0; mi < 4; mi++)
                af[mi] = *(const bf16x8*)&AsmF[(wm + mi * 16 + col) * 64 +
                                               (((ks << 2) + quad) ^ cswz) * 8];
            for (int ni = 0; ni < 4; ni++)
                bfr[ni] = *(const bf16x8*)&BsmF[(wn + ni * 16 + col) * 64 +
                                                (((ks << 2) + quad) ^ cswz) * 8];
            if (which != 2) {
                for (int mi = 0; mi < 4; mi++)
                    for (int ni = 0; ni < 4; ni++)
                        acc[mi][ni] = MFMA16(af[mi], bfr[ni], acc[mi][ni]);
            } else {
                for (int mi = 0; mi < 4; mi++)
                    for (int ni = 0; ni < 4; ni++)
                        acc[mi][ni] = MFMA16(bfr[ni], af[mi], acc[mi][ni]);
            }
        }
        __syncthreads();
    }

    if (which != 2) {
        const float sc = (which == 0) ? QSCALE : 1.0f;
        for (int mi = 0; mi < 4; mi++) {
            for (int ni = 0; ni < 4; ni++) {
                int mbase = bm + wm + mi * 16 + quad * 4;
                int n = bn + wn + ni * 16 + col;
                int h = n >> 6, dh = n & 63;
                for (int r = 0; r < 4; r++) {
                    int m = mbase + r;
                    int b = m >> 11, s = m & 2047;
                    size_t bh = (size_t)b * 16 + h;
                    bf16_t val = (bf16_t)(acc[mi][ni][r] * sc);
                    if (which == 0) Qd[(bh * 2048 + s) * 64 + dh] = val;
                    else            Kd[(bh * 2048 + s) * 64 + dh] = val;
                }
            }
        }
    } else {
        for (int mi = 0; mi < 4; mi++) {
            for (int ni = 0; ni < 4; ni++) {
                int nbase = bn + wn + ni * 16 + quad * 4;
                int m = bm + wm + mi * 16 + col;
                int b = m >> 11, s = m & 2047;
                for (int r = 0; r < 4; r++) {
                    int n = nbase + r;
                    int h = n >> 6, dh = n & 63;
                    size_t bh = (size_t)b * 16 + h;
                    Vd[(bh * 64 + dh) * 2048 + s] = (bf16_t)acc[mi][ni][r];
                }
            }
        }
    }
}

// ---------------------------------------------------------------------------
// Flash attention (causal): ONE q-tile per block, grid 1024 = 3 blocks/CU
// (12 waves/CU, was 8). Longest-first: qt = 31-(bidx>>5) so heavy blocks
// dispatch first and qt 0..7 blocks backfill the tail. XCD-local bh = bidx&31.
// Prefetch pipeline + pre-scaled Q (exp2f) + ones-MFMA denominator.
// ---------------------------------------------------------------------------
#define PSD 72
__global__ __launch_bounds__(256) void attn(const bf16_t* __restrict__ Q,
                                            const bf16_t* __restrict__ K,
                                            const bf16_t* __restrict__ VT,
                                            bf16_t* __restrict__ CTX) {
    __shared__ bf16_t KsF[2 * 64 * 64];
    __shared__ bf16_t VsF[2 * 64 * 64];
    __shared__ bf16_t Ps[4][16][PSD];

    const int bidx = blockIdx.x;
    const int bh = bidx & 31;        // XCD-local: bidx%8 == bh%8
    const int qt = 31 - (bidx >> 5); // longest-first dispatch order
    const int tid = threadIdx.x;
    const int wave = tid >> 6, lane = tid & 63;
    const int col = lane & 15, quad = lane >> 4;
    const int cswz = col & 7;
    const int lr8 = lane >> 3;
    const int jg = (lane & 7) ^ lr8;

    const bf16_t* Qb = Q + (size_t)bh * 2048 * 64;
    const bf16_t* Kb = K + (size_t)bh * 2048 * 64;
    const bf16_t* Vb = VT + (size_t)bh * 64 * 2048;

    const int strow = wave * 16 + lr8;
    const bf16_t* gK = Kb + (size_t)strow * 64 + jg * 8;
    const bf16_t* gV = Vb + (size_t)strow * 2048 + jg * 8;

    const int b_ = bh >> 4, h_ = bh & 15;

    bf16x8 ones;
    for (int i = 0; i < 8; i++) ones[i] = (bf16_t)1.0f;

    auto stage = [&](int k0, int bsel) {
        bf16_t* lK = KsF + bsel * 4096 + wave * 1024;
        bf16_t* lV = VsF + bsel * 4096 + wave * 1024;
        for (int j = 0; j < 2; j++) {
            GLL16(gK + (size_t)(k0 + j * 8) * 64, lK + j * 512);
            GLL16(gV + (size_t)(k0 + j * 8 * 2048), lV + j * 512);
        }
    };

    stage(0, 0);  // prologue

    const int q0 = qt * 64;
    const int qrow = q0 + wave * 16 + col;
    const bf16x8 qf0 = *(const bf16x8*)&Qb[(size_t)qrow * 64 + quad * 8];
    const bf16x8 qf1 = *(const bf16x8*)&Qb[(size_t)qrow * 64 + 32 + quad * 8];

    f32x4 o[4] = {};
    f32x4 accl = {};   // l[q]: reg r holds l[quad*4+r], replicated over cols

    const int nt = qt + 1;
    for (int g = 0; g < nt; g++) {
        __syncthreads();   // buf[g&1] ready; compute(g-1) done -> buf[(g+1)&1] free
        if (g + 1 < nt) stage((g + 1) * 64, (g + 1) & 1);

        const int bsel = g & 1;
        const bf16_t* Kbuf = KsF + bsel * 4096;
        const bf16_t* Vbuf = VsF + bsel * 4096;
        const bool diag = (g == qt);

        for (int ksub = 0; ksub < 4; ksub++) {
            bf16x8 a0 = *(const bf16x8*)&Kbuf[(ksub * 16 + col) * 64 +
                                              (quad ^ cswz) * 8];
            bf16x8 a1 = *(const bf16x8*)&Kbuf[(ksub * 16 + col) * 64 +
                                              ((4 + quad) ^ cswz) * 8];
            f32x4 z = {};
            z = MFMA16(a0, qf0, z);   // S^T: rows=key, cols=q (Q pre-scaled)
            z = MFMA16(a1, qf1, z);
            if (diag) {
                for (int r = 0; r < 4; r++) {
                    int lk = ksub * 16 + quad * 4 + r;
                    if (lk > wave * 16 + col) z[r] = NEG_BIG;
                }
            }
            bf16x4 pw;
            for (int r = 0; r < 4; r++)
                pw[r] = (bf16_t)exp2f(z[r]);   // p = e^{qk/8}; masked -> 0
            *(bf16x4*)&Ps[wave][col][ksub * 16 + quad * 4] = pw;
        }

        for (int ck = 0; ck < 2; ck++) {
            bf16x8 pf = *(const bf16x8*)&Ps[wave][col][ck * 32 + quad * 8];
            accl = MFMA16(pf, ones, accl);     // l[q] += sum_k P[q][k]
            for (int d = 0; d < 4; d++) {
                bf16x8 vf = *(const bf16x8*)&Vbuf[(d * 16 + col) * 64 +
                                                  (((ck << 2) + quad) ^ cswz) * 8];
                o[d] = MFMA16(pf, vf, o[d]);
            }
        }
    }

    for (int d = 0; d < 4; d++) {
        for (int r = 0; r < 4; r++) {
            int s = q0 + wave * 16 + quad * 4 + r;
            CTX[((size_t)(b_ * 2048 + s)) * 1024 + h_ * 64 + d * 16 + col] =
                (bf16_t)(o[d][r] / fmaxf(accl[r], 1e-20f));
        }
    }
}

// ---------------------------------------------------------------------------
// Output GEMM: OUT = CTX @ Wo + bo. 64x128 tile (512 blocks), BK=64,
// global_load_lds staging. Waves 2x2 of 32x64.
// ---------------------------------------------------------------------------
__global__ __launch_bounds__(256) void gemm_out(const bf16_t* __restrict__ X,
                                                const bf16_t* __restrict__ WT,
                                                const float* __restrict__ BO,
                                                float* __restrict__ OUT) {
    __shared__ bf16_t AsmF[64 * 64];
    __shared__ bf16_t BsmF[128 * 64];
    const int bm = blockIdx.y * 64;
    const int bn = blockIdx.x * 128;
    const int tid = threadIdx.x;
    const int wave = tid >> 6, lane = tid & 63;
    const int wm = (wave >> 1) * 32, wn = (wave & 1) * 64;
    const int col = lane & 15, quad = lane >> 4;
    const int cswz = col & 7;
    const int lr8 = lane >> 3;
    const int jg = (lane & 7) ^ lr8;

    const int arow = wave * 16 + lr8;
    const int brow = wave * 32 + lr8;
    const bf16_t* gA = X  + (size_t)(bm + arow) * 1024 + jg * 8;
    const bf16_t* gB = WT + (size_t)(bn + brow) * 1024 + jg * 8;
    bf16_t* lA = AsmF + wave * 1024;
    bf16_t* lB = BsmF + wave * 2048;

    f32x4 acc[2][4] = {};

    for (int k0 = 0; k0 < 1024; k0 += 64) {
        for (int j = 0; j < 2; j++)
            GLL16(gA + (size_t)j * 8192 + k0, lA + j * 512);
        for (int j = 0; j < 4; j++)
            GLL16(gB + (size_t)j * 8192 + k0, lB + j * 512);
        __syncthreads();
        for (int ks = 0; ks < 2; ks++) {
            bf16x8 af[2], bfr[4];
            for (int mi = 0; mi < 2; mi++)
                af[mi] = *(const bf16x8*)&AsmF[(wm + mi * 16 + col) * 64 +
                                               (((ks << 2) + quad) ^ cswz) * 8];
            for (int ni = 0; ni < 4; ni++)
                bfr[ni] = *(const bf16x8*)&BsmF[(wn + ni * 16 + col) * 64 +
                                                (((ks << 2) + quad) ^ cswz) * 8];
            for (int mi = 0; mi < 2; mi++)
                for (int ni = 0; ni < 4; ni++)
                    acc[mi][ni] = MFMA16(af[mi], bfr[ni], acc[mi][ni]);
        }
        __syncthreads();
    }

    for (int mi = 0; mi < 2; mi++) {
        for (int ni = 0; ni < 4; ni++) {
            int mbase = bm + wm + mi * 16 + quad * 4;
            int n = bn + wn + ni * 16 + col;
            float bov = BO[n];
            for (int r = 0; r < 4; r++) {
                int m = mbase + r;
                OUT[(size_t)m * 1024 + n] = acc[mi][ni][r] + bov;
            }
        }
    }
}

// ---------------------------------------------------------------------------
extern "C" void kernel_launch(void* const* d_in, const int* in_sizes, int n_in,
                              void* d_out, int out_size, void* d_ws, size_t ws_size,
                              hipStream_t stream) {
    const float* x  = (const float*)d_in[0];
    const float* Wq = (const float*)d_in[1];
    const float* Wk = (const float*)d_in[2];
    const float* Wv = (const float*)d_in[3];
    const float* Wo = (const float*)d_in[4];
    const float* bo = (const float*)d_in[5];
    float* out = (float*)d_out;

    const size_t MEG = 1048576;
    bf16_t* base  = (bf16_t*)d_ws;
    bf16_t* Xb    = base;                 // 4M elems  [4096][1024]
    bf16_t* WTqkv = base + 4 * MEG;       // 3M (WqT, WkT, WvT)
    bf16_t* WoT   = base + 7 * MEG;       // 1M
    bf16_t* Qb    = base + 8 * MEG;       // 4M  [32][2048][64]
    bf16_t* Kb    = base + 12 * MEG;      // 4M
    bf16_t* Vb    = base + 16 * MEG;      // 4M  [32][64][2048]
    bf16_t* Cb    = base + 20 * MEG;      // 4M  [4096][1024]

    prep<<<dim3(32, 32, 5), dim3(32, 8), 0, stream>>>(x, Wq, Wk, Wv, Wo,
                                                      Xb, WTqkv, WoT);
    gemm_qkv<<<dim3(8, 32, 3), 256, 0, stream>>>(Xb, WTqkv, Qb, Kb, Vb);
    attn<<<1024, 256, 0, stream>>>(Qb, Kb, Vb, Cb);
    gemm_out<<<dim3(8, 64), 256, 0, stream>>>(Cb, WoT, bo, out);
}